// Round 7
// baseline (638.970 us; speedup 1.0000x reference)
//
#include <hip/hip_runtime.h>
#include <math.h>

#define Bq 8
#define Tq 2048
#define Dq 1024
#define Mq (Bq*Tq)          // 16384 rows
#define NCHq 32             // chunks per channel
#define CHUNKq 64           // timesteps per chunk
#define DECAYq 0.99f
#define DF64q 0.52559646f   // 0.99^64

typedef unsigned short u16;
typedef unsigned int u32;
typedef __attribute__((ext_vector_type(8))) short bf16x8;
typedef __attribute__((ext_vector_type(4))) float f32x4;
typedef __attribute__((ext_vector_type(4))) u16 u16x4;

__device__ __forceinline__ u16 f2bf(float f) {
  u32 u = __builtin_bit_cast(u32, f);
  return (u16)((u + 0x7FFFu + ((u >> 16) & 1u)) >> 16);
}
__device__ __forceinline__ float bf2f(u16 h) {
  return __builtin_bit_cast(float, (u32)h << 16);
}
__device__ __forceinline__ float sigm(float x) { return 1.0f / (1.0f + expf(-x)); }

// ---------------- weight prep: fp32 [K][N] -> bf16 [N][K] ----------------
__global__ __launch_bounds__(256)
void transpose_bf16(const float* __restrict__ src, u16* __restrict__ dst, int K, int N) {
  __shared__ float tile[32][33];
  const int n0 = blockIdx.x << 5;
  const int k0 = blockIdx.y << 5;
  const int tx = threadIdx.x & 31;
  const int ty = threadIdx.x >> 5;   // 0..7
#pragma unroll
  for (int j = 0; j < 32; j += 8)
    tile[ty + j][tx] = src[(size_t)(k0 + ty + j) * N + (n0 + tx)];
  __syncthreads();
#pragma unroll
  for (int j = 0; j < 32; j += 8)
    dst[(size_t)(n0 + ty + j) * K + (k0 + tx)] = f2bf(tile[tx][ty + j]);
}

// ---------------- LayerNorm: one row (1024 f32) per 256-thread block ------
__global__ __launch_bounds__(256)
void ln_kernel(const float* __restrict__ xin, const float* __restrict__ w,
               const float* __restrict__ bb, u16* __restrict__ obf) {
  const int row = blockIdx.x;
  const int tid = threadIdx.x;
  const float4 v = ((const float4*)(xin + (size_t)row * Dq))[tid];
  float s  = v.x + v.y + v.z + v.w;
  float s2 = v.x*v.x + v.y*v.y + v.z*v.z + v.w*v.w;
#pragma unroll
  for (int o = 32; o > 0; o >>= 1) { s += __shfl_xor(s, o); s2 += __shfl_xor(s2, o); }
  __shared__ float rs[4], rq[4];
  const int wid = tid >> 6;
  if ((tid & 63) == 0) { rs[wid] = s; rq[wid] = s2; }
  __syncthreads();
  s  = rs[0] + rs[1] + rs[2] + rs[3];
  s2 = rq[0] + rq[1] + rq[2] + rq[3];
  const float mu  = s * (1.0f/Dq);
  const float var = s2 * (1.0f/Dq) - mu*mu;
  const float inv = rsqrtf(var + 1e-5f);
  const float4 wv = ((const float4*)w)[tid];
  const float4 bv = ((const float4*)bb)[tid];
  float4 o;
  o.x = (v.x - mu)*inv*wv.x + bv.x;
  o.y = (v.y - mu)*inv*wv.y + bv.y;
  o.z = (v.z - mu)*inv*wv.z + bv.z;
  o.w = (v.w - mu)*inv*wv.w + bv.w;
  u16x4 ob; ob[0] = f2bf(o.x); ob[1] = f2bf(o.y); ob[2] = f2bf(o.z); ob[3] = f2bf(o.w);
  ((u16x4*)(obf + (size_t)row * Dq))[tid] = ob;
}

// ---------------- chunked decay scan (bf16 in/out, fp32 accumulate) -------
// grid: B*NCH*(D/256) blocks; block -> (b, chunk c, d-block)
template<bool REV>
__global__ __launch_bounds__(256)
void scan_pass1(const u16* __restrict__ v, float* __restrict__ ce) {
  const int dblk = blockIdx.x & 3;
  const int c    = (blockIdx.x >> 2) & 31;
  const int b    = blockIdx.x >> 7;
  const int d    = (dblk << 8) + threadIdx.x;
  float e = 0.0f;
  for (int i = 0; i < CHUNKq; ++i) {
    const int tt = c * CHUNKq + i;
    const int t  = REV ? (Tq - 1 - tt) : tt;
    e = DECAYq * e + bf2f(v[((size_t)b * Tq + t) * Dq + d]);
  }
  ce[((size_t)b * NCHq + c) * Dq + d] = e;
}

__global__ __launch_bounds__(256)
void scan_pass2(const float* __restrict__ ce, float* __restrict__ car) {
  const int idx = blockIdx.x * 256 + threadIdx.x;  // 0..8191 -> (b,d)
  const int b = idx >> 10;
  const int d = idx & 1023;
  float c = 0.0f;
  for (int k = 0; k < NCHq; ++k) {
    const size_t i = ((size_t)b * NCHq + k) * Dq + d;
    car[i] = c;
    c = DF64q * c + ce[i];
  }
}

// in-place: v (bf16) -> h (bf16)
template<bool REV>
__global__ __launch_bounds__(256)
void scan_pass3(u16* __restrict__ v, const float* __restrict__ car) {
  const int dblk = blockIdx.x & 3;
  const int c    = (blockIdx.x >> 2) & 31;
  const int b    = blockIdx.x >> 7;
  const int d    = (dblk << 8) + threadIdx.x;
  float hc = car[((size_t)b * NCHq + c) * Dq + d];
  for (int i = 0; i < CHUNKq; ++i) {
    const int tt = c * CHUNKq + i;
    const int t  = REV ? (Tq - 1 - tt) : tt;
    const size_t idx = ((size_t)b * Tq + t) * Dq + d;
    hc = DECAYq * hc + bf2f(v[idx]);
    v[idx] = f2bf(hc);
  }
}

// ---------------- fused epilogues ----------------
struct EpiGate {   // merged fwd|bwd gate: c<1024 -> fwd, else bwd
  const u16* h; const float* mask; const float* bgf; const float* bgb;
  u16* vf; u16* vb;
  __device__ void operator()(int r, int c, float val) const {
    const bool fwd = c < 1024;
    const int cc = c & 1023;
    const float s = sigm(val + (fwd ? bgf[cc] : bgb[cc]));
    const float hv = bf2f(h[(size_t)r * Dq + cc]) * mask[r];
    (fwd ? vf : vb)[(size_t)r * Dq + cc] = f2bf(s * hv);
  }
};
struct EpiFuse {
  const float* bfuse; const float* x; const u16* hf; const u16* hb; float* x2;
  __device__ void operator()(int r, int c, float val) const {
    const size_t i = (size_t)r * Dq + c;
    const float bta = sigm(val + bfuse[c]);
    x2[i] = x[i] + bta * bf2f(hf[i]) + (1.0f - bta) * bf2f(hb[i]);
  }
};
struct EpiFfn1 {
  const float* b1; u16* a;
  __device__ void operator()(int r, int c, float val) const {
    const float u = val + b1[c];
    const float g = 0.5f * u * (1.0f + erff(u * 0.70710678118f));
    a[(size_t)r * 2048 + c] = f2bf(g);
  }
};
struct EpiFfn2 {
  const float* b2; const float* x2; float* o;
  __device__ void operator()(int r, int c, float val) const {
    const size_t i = (size_t)r * Dq + c;
    o[i] = val + b2[c] + x2[i];
  }
};

// ---------------- bf16 MFMA GEMM: C = A(MxK) * BT(NxK)^T, 256x128 tile ----
// 8 waves (4M x 2N), per-wave 64x64 output (acc 4x4: 16 ds_read_b128 vs
// 32 MFMA per K-step — feeds the matrix pipe, unlike 64x32 which was
// LDS-read-bound). Ring-3 LDS (144 KiB), prefetch distance 2, counted
// vmcnt(6) that never drains to 0 in steady state, ONE barrier per K-step:
//   iter kt: sched_barrier(0); s_waitcnt vmcnt(6) lgkmcnt(0); s_barrier;
//            stage(kt+2 -> buf[(kt+2)%3]); compute(buf[kt%3]).
// Safety invariant: buf[(kt+2)%3] was last read in iter kt-1; every wave's
// ds_reads completed (lgkmcnt(0)) before its iter-kt barrier, so post-barrier
// DMA writes cannot race any reader. vmcnt(6) leaves exactly tile kt+1's 6
// loads in flight; tile kt's loads were issued 2 K-steps (~2500 cyc) ago.
// A may be split at column ksplit into two buffers (A for k<ksplit, A2 after).
template<typename Epi>
__global__ __launch_bounds__(512)
void gemm_bt(const u16* __restrict__ A, const u16* __restrict__ A2, int ksplit,
             const u16* __restrict__ BT, int K, int nx, Epi epi) {
  __shared__ u16 As[3][16384];  // 3 x [256][64] bf16 (32 KiB each), XOR-swizzled rows
  __shared__ u16 Bs[3][8192];   // 3 x [128][64] bf16 (16 KiB each)
  const int tid  = threadIdx.x;
  const int lane = tid & 63;
  const int w    = tid >> 6;    // 0..7
  const int wr   = w >> 1;      // 0..3 (64-row band)
  const int wc   = w & 1;       // 0..1 (64-col band)

  // XCD-aware remap: HW sends dispatch index lin to XCD lin%8; give XCD k the
  // contiguous logical-tile range [k*q, (k+1)*q), col-panel fastest.
  const int lin = blockIdx.x;
  const int q8  = gridDim.x >> 3;
  const int t   = (lin & 7) * q8 + (lin >> 3);
  const int by  = t / nx;
  const int bx  = t - by * nx;
  const int rowBase = by << 8;   // 256-row tiles
  const int colBase = bx << 7;   // 128-col tiles

  // staging: 512 threads cover 64 rows x 128B per issue; A=4 issues, B=2.
  // linear LDS dest (wave-uniform base + lane*16B), swizzled global source col.
  const int srow  = tid >> 3;                              // 0..63
  const int scolE = (((tid & 7) ^ (srow & 7)) << 4) >> 1;  // element col in source row
  const int KA    = (ksplit < K) ? ksplit : K;             // row stride of A buffers

  auto stage = [&](int buf, int kt) {
    const int kbase = kt << 6;
    const u16* Abase = (kbase < ksplit) ? A : A2;
    const int  kA    = (kbase < ksplit) ? kbase : (kbase - ksplit);
#pragma unroll
    for (int qq = 0; qq < 4; ++qq) {
      const u16* ga = Abase + (size_t)(rowBase + (qq << 6) + srow) * KA + kA + scolE;
      __builtin_amdgcn_global_load_lds(
          (const __attribute__((address_space(1))) void*)ga,
          (__attribute__((address_space(3))) void*)((char*)&As[buf][0] + (qq << 13) + (tid << 4)),
          16, 0, 0);
    }
#pragma unroll
    for (int qq = 0; qq < 2; ++qq) {
      const u16* gb = BT + (size_t)(colBase + (qq << 6) + srow) * K + kbase + scolE;
      __builtin_amdgcn_global_load_lds(
          (const __attribute__((address_space(1))) void*)gb,
          (__attribute__((address_space(3))) void*)((char*)&Bs[buf][0] + (qq << 13) + (tid << 4)),
          16, 0, 0);
    }
  };

  f32x4 acc[4][4];
#pragma unroll
  for (int m = 0; m < 4; ++m)
#pragma unroll
    for (int n = 0; n < 4; ++n) acc[m][n] = (f32x4){0.f, 0.f, 0.f, 0.f};

  const int nkt = K >> 6;       // 16 or 32 (always >= 3)
  stage(0, 0);
  stage(1, 1);

  int cbuf = 0, sbuf = 2;
  for (int kt = 0; kt < nkt; ++kt) {
    __builtin_amdgcn_sched_barrier(0);
    if (kt < nkt - 1) asm volatile("s_waitcnt vmcnt(6) lgkmcnt(0)" ::: "memory");
    else              asm volatile("s_waitcnt vmcnt(0) lgkmcnt(0)" ::: "memory");
    __builtin_amdgcn_s_barrier();
    if (kt + 2 < nkt) stage(sbuf, kt + 2);
    const char* Ab = (const char*)&As[cbuf][0];
    const char* Bb = (const char*)&Bs[cbuf][0];
#pragma unroll
    for (int kk = 0; kk < 2; ++kk) {
      bf16x8 af[4], bfr[4];
      const int cb = (kk << 6) + ((lane >> 4) << 4);   // byte col within 128B row
#pragma unroll
      for (int m = 0; m < 4; ++m) {
        const int r = (wr << 6) + (m << 4) + (lane & 15);
        af[m] = *(const bf16x8*)(Ab + (r << 7) + (cb ^ ((r & 7) << 4)));
      }
#pragma unroll
      for (int n = 0; n < 4; ++n) {
        const int r = (wc << 6) + (n << 4) + (lane & 15);
        bfr[n] = *(const bf16x8*)(Bb + (r << 7) + (cb ^ ((r & 7) << 4)));
      }
      __builtin_amdgcn_s_setprio(1);
#pragma unroll
      for (int m = 0; m < 4; ++m)
#pragma unroll
        for (int n = 0; n < 4; ++n)
          acc[m][n] = __builtin_amdgcn_mfma_f32_16x16x32_bf16(af[m], bfr[n], acc[m][n], 0, 0, 0);
      __builtin_amdgcn_s_setprio(0);
    }
    cbuf = (cbuf == 2) ? 0 : cbuf + 1;
    sbuf = (sbuf == 2) ? 0 : sbuf + 1;
  }

  // epilogue: C/D layout col = lane&15, row = (lane>>4)*4 + reg
#pragma unroll
  for (int m = 0; m < 4; ++m) {
    const int grow0 = rowBase + (wr << 6) + (m << 4) + ((lane >> 4) << 2);
#pragma unroll
    for (int n = 0; n < 4; ++n) {
      const int gcol = colBase + (wc << 6) + (n << 4) + (lane & 15);
#pragma unroll
      for (int r2 = 0; r2 < 4; ++r2)
        epi(grow0 + r2, gcol, acc[m][n][r2]);
    }
  }
}

// ---------------- launcher ----------------
extern "C" void kernel_launch(void* const* d_in, const int* in_sizes, int n_in,
                              void* d_out, int out_size, void* d_ws, size_t ws_size,
                              hipStream_t stream) {
  (void)in_sizes; (void)n_in; (void)out_size; (void)ws_size;
  const float* x      = (const float*)d_in[0];
  const float* mask   = (const float*)d_in[1];
  const float* ln1w   = (const float*)d_in[2];
  const float* ln1b   = (const float*)d_in[3];
  const float* ln2w   = (const float*)d_in[4];
  const float* ln2b   = (const float*)d_in[5];
  const float* Wg_f   = (const float*)d_in[6];
  const float* bg_f   = (const float*)d_in[7];
  const float* Wg_b   = (const float*)d_in[8];
  const float* bg_b   = (const float*)d_in[9];
  const float* W_fuse = (const float*)d_in[10];
  const float* b_fuse = (const float*)d_in[11];
  const float* W_ffn1 = (const float*)d_in[12];
  const float* b_ffn1 = (const float*)d_in[13];
  const float* W_ffn2 = (const float*)d_in[14];
  const float* b_ffn2 = (const float*)d_in[15];
  float* out = (float*)d_out;

  // ---- workspace layout: ~178 MiB total ----
  char* ws = (char*)d_ws;
  size_t off = 0;
  auto alloc = [&](size_t bytes) { char* p = ws + off; off += (bytes + 255) & ~(size_t)255; return p; };
  float* x2     = (float*)alloc((size_t)Mq * Dq * 4);      // 64 MiB, live steps 7-10
  u16*   slotA  = (u16*)  alloc((size_t)Mq * Dq * 2);      // 32 MiB: h_bf16 -> y2
  u16*   hf_bf  = (u16*)  alloc((size_t)Mq * Dq * 2);      // 32 MiB: v_fwd -> h_fwd (in place) -> a lo
  u16*   hb_bf  = (u16*)  alloc((size_t)Mq * Dq * 2);      // 32 MiB: v_bwd -> h_bwd (in place) -> a hi
  u16*   WgT    = (u16*)  alloc((size_t)2048 * 1024 * 2);  // 4 MiB [2048][1024] (fwd rows | bwd rows)
  u16*   WfuT   = (u16*)  alloc((size_t)1024 * 2048 * 2);  // 4 MiB [1024][2048]
  u16*   Wf1T   = (u16*)  alloc((size_t)2048 * 1024 * 2);  // 4 MiB [2048][1024]
  u16*   Wf2T   = (u16*)  alloc((size_t)1024 * 2048 * 2);  // 4 MiB [1024][2048]
  float* ce     = (float*)alloc((size_t)Bq * NCHq * Dq * 4); // 1 MiB (shared both dirs)
  float* car    = (float*)alloc((size_t)Bq * NCHq * Dq * 4); // 1 MiB
  u16*   h_bf16 = slotA;
  u16*   y2     = slotA;
  u16*   a_bf16 = hf_bf;   // hf|hb contiguous 64 MiB -> [M][2048] FFN1 activations

  // 1. weight prep (transpose + bf16); gate weights concatenated along N
  transpose_bf16<<<dim3(32, 32), 256, 0, stream>>>(Wg_f, WgT, 1024, 1024);
  transpose_bf16<<<dim3(32, 32), 256, 0, stream>>>(Wg_b, WgT + 1024 * 1024, 1024, 1024);
  transpose_bf16<<<dim3(32, 64), 256, 0, stream>>>(W_fuse, WfuT, 2048, 1024);
  transpose_bf16<<<dim3(64, 32), 256, 0, stream>>>(W_ffn1, Wf1T, 1024, 2048);
  transpose_bf16<<<dim3(32, 64), 256, 0, stream>>>(W_ffn2, Wf2T, 2048, 1024);

  // 2. LN1: x -> h_bf16
  ln_kernel<<<Mq, 256, 0, stream>>>(x, ln1w, ln1b, h_bf16);

  const int sg = Bq * NCHq * (Dq / 256);

  // 3. merged gate GEMM (N=2048 = fwd|bwd) -> v_fwd, v_bwd (bf16)
  EpiGate eg{h_bf16, mask, bg_f, bg_b, hf_bf, hb_bf};
  gemm_bt<EpiGate><<<16 * (Mq / 256), 512, 0, stream>>>(h_bf16, h_bf16, 1024, WgT, 1024, 16, eg);

  // 4. decay scans, in-place bf16 v -> h
  scan_pass1<false><<<sg, 256, 0, stream>>>(hf_bf, ce);
  scan_pass2<<<(Bq * Dq) / 256, 256, 0, stream>>>(ce, car);
  scan_pass3<false><<<sg, 256, 0, stream>>>(hf_bf, car);
  scan_pass1<true ><<<sg, 256, 0, stream>>>(hb_bf, ce);
  scan_pass2<<<(Bq * Dq) / 256, 256, 0, stream>>>(ce, car);
  scan_pass3<true ><<<sg, 256, 0, stream>>>(hb_bf, car);

  // 7. fusion GEMM (K=2048, A split hf|hb), epilogue: beta-blend + residual -> x2
  EpiFuse ef{b_fuse, x, hf_bf, hb_bf, x2};
  gemm_bt<EpiFuse><<<8 * (Mq / 256), 512, 0, stream>>>(hf_bf, hb_bf, 1024, WfuT, 2048, 8, ef);

  // 8. LN2: x2 -> y2 (overwrites h_bf16 slot, no longer needed)
  ln_kernel<<<Mq, 256, 0, stream>>>(x2, ln2w, ln2b, y2);

  // 9. FFN1 (N=2048) + exact GELU -> a_bf16 (overwrites hf|hb, dead after fuse)
  EpiFfn1 e1{b_ffn1, a_bf16};
  gemm_bt<EpiFfn1><<<16 * (Mq / 256), 512, 0, stream>>>(y2, y2, 1024, Wf1T, 1024, 16, e1);

  // 10. FFN2 (K=2048) + bias + residual -> out
  EpiFfn2 e2{b_ffn2, x2, out};
  gemm_bt<EpiFfn2><<<8 * (Mq / 256), 512, 0, stream>>>(a_bf16, a_bf16, 2048, Wf2T, 2048, 8, e2);
}

// Round 8
// 603.342 us; speedup vs baseline: 1.0591x; 1.0591x over previous
//
#include <hip/hip_runtime.h>
#include <math.h>

#define Bq 8
#define Tq 2048
#define Dq 1024
#define Mq (Bq*Tq)          // 16384 rows
#define NCHq 32             // chunks per channel
#define CHUNKq 64           // timesteps per chunk
#define DECAYq 0.99f
#define DF64q 0.52559646f   // 0.99^64

typedef unsigned short u16;
typedef unsigned int u32;
typedef __attribute__((ext_vector_type(8))) short bf16x8;
typedef __attribute__((ext_vector_type(4))) float f32x4;
typedef __attribute__((ext_vector_type(4))) u16 u16x4;

__device__ __forceinline__ u16 f2bf(float f) {
  u32 u = __builtin_bit_cast(u32, f);
  return (u16)((u + 0x7FFFu + ((u >> 16) & 1u)) >> 16);
}
__device__ __forceinline__ float bf2f(u16 h) {
  return __builtin_bit_cast(float, (u32)h << 16);
}
__device__ __forceinline__ float sigm(float x) { return 1.0f / (1.0f + expf(-x)); }

// ---------------- weight prep: fp32 [K][N] -> bf16 [N][K] ----------------
__global__ __launch_bounds__(256)
void transpose_bf16(const float* __restrict__ src, u16* __restrict__ dst, int K, int N) {
  __shared__ float tile[32][33];
  const int n0 = blockIdx.x << 5;
  const int k0 = blockIdx.y << 5;
  const int tx = threadIdx.x & 31;
  const int ty = threadIdx.x >> 5;   // 0..7
#pragma unroll
  for (int j = 0; j < 32; j += 8)
    tile[ty + j][tx] = src[(size_t)(k0 + ty + j) * N + (n0 + tx)];
  __syncthreads();
#pragma unroll
  for (int j = 0; j < 32; j += 8)
    dst[(size_t)(n0 + ty + j) * K + (k0 + tx)] = f2bf(tile[tx][ty + j]);
}

// ---------------- LayerNorm: one row (1024 f32) per 256-thread block ------
__global__ __launch_bounds__(256)
void ln_kernel(const float* __restrict__ xin, const float* __restrict__ w,
               const float* __restrict__ bb, u16* __restrict__ obf) {
  const int row = blockIdx.x;
  const int tid = threadIdx.x;
  const float4 v = ((const float4*)(xin + (size_t)row * Dq))[tid];
  float s  = v.x + v.y + v.z + v.w;
  float s2 = v.x*v.x + v.y*v.y + v.z*v.z + v.w*v.w;
#pragma unroll
  for (int o = 32; o > 0; o >>= 1) { s += __shfl_xor(s, o); s2 += __shfl_xor(s2, o); }
  __shared__ float rs[4], rq[4];
  const int wid = tid >> 6;
  if ((tid & 63) == 0) { rs[wid] = s; rq[wid] = s2; }
  __syncthreads();
  s  = rs[0] + rs[1] + rs[2] + rs[3];
  s2 = rq[0] + rq[1] + rq[2] + rq[3];
  const float mu  = s * (1.0f/Dq);
  const float var = s2 * (1.0f/Dq) - mu*mu;
  const float inv = rsqrtf(var + 1e-5f);
  const float4 wv = ((const float4*)w)[tid];
  const float4 bv = ((const float4*)bb)[tid];
  float4 o;
  o.x = (v.x - mu)*inv*wv.x + bv.x;
  o.y = (v.y - mu)*inv*wv.y + bv.y;
  o.z = (v.z - mu)*inv*wv.z + bv.z;
  o.w = (v.w - mu)*inv*wv.w + bv.w;
  u16x4 ob; ob[0] = f2bf(o.x); ob[1] = f2bf(o.y); ob[2] = f2bf(o.z); ob[3] = f2bf(o.w);
  ((u16x4*)(obf + (size_t)row * Dq))[tid] = ob;
}

// ---------------- chunked decay scan (bf16 in/out, fp32 accumulate) -------
template<bool REV>
__global__ __launch_bounds__(256)
void scan_pass1(const u16* __restrict__ v, float* __restrict__ ce) {
  const int dblk = blockIdx.x & 3;
  const int c    = (blockIdx.x >> 2) & 31;
  const int b    = blockIdx.x >> 7;
  const int d    = (dblk << 8) + threadIdx.x;
  float e = 0.0f;
  for (int i = 0; i < CHUNKq; ++i) {
    const int tt = c * CHUNKq + i;
    const int t  = REV ? (Tq - 1 - tt) : tt;
    e = DECAYq * e + bf2f(v[((size_t)b * Tq + t) * Dq + d]);
  }
  ce[((size_t)b * NCHq + c) * Dq + d] = e;
}

__global__ __launch_bounds__(256)
void scan_pass2(const float* __restrict__ ce, float* __restrict__ car) {
  const int idx = blockIdx.x * 256 + threadIdx.x;  // 0..8191 -> (b,d)
  const int b = idx >> 10;
  const int d = idx & 1023;
  float c = 0.0f;
  for (int k = 0; k < NCHq; ++k) {
    const size_t i = ((size_t)b * NCHq + k) * Dq + d;
    car[i] = c;
    c = DF64q * c + ce[i];
  }
}

// in-place: v (bf16) -> h (bf16)
template<bool REV>
__global__ __launch_bounds__(256)
void scan_pass3(u16* __restrict__ v, const float* __restrict__ car) {
  const int dblk = blockIdx.x & 3;
  const int c    = (blockIdx.x >> 2) & 31;
  const int b    = blockIdx.x >> 7;
  const int d    = (dblk << 8) + threadIdx.x;
  float hc = car[((size_t)b * NCHq + c) * Dq + d];
  for (int i = 0; i < CHUNKq; ++i) {
    const int tt = c * CHUNKq + i;
    const int t  = REV ? (Tq - 1 - tt) : tt;
    const size_t idx = ((size_t)b * Tq + t) * Dq + d;
    hc = DECAYq * hc + bf2f(v[idx]);
    v[idx] = f2bf(hc);
  }
}

// ---------------- fused epilogues ----------------
struct EpiGate {   // merged fwd|bwd gate: c<1024 -> fwd, else bwd
  const u16* h; const float* mask; const float* bgf; const float* bgb;
  u16* vf; u16* vb;
  __device__ void operator()(int r, int c, float val) const {
    const bool fwd = c < 1024;
    const int cc = c & 1023;
    const float s = sigm(val + (fwd ? bgf[cc] : bgb[cc]));
    const float hv = bf2f(h[(size_t)r * Dq + cc]) * mask[r];
    (fwd ? vf : vb)[(size_t)r * Dq + cc] = f2bf(s * hv);
  }
};
struct EpiFuse {
  const float* bfuse; const float* x; const u16* hf; const u16* hb; float* x2;
  __device__ void operator()(int r, int c, float val) const {
    const size_t i = (size_t)r * Dq + c;
    const float bta = sigm(val + bfuse[c]);
    x2[i] = x[i] + bta * bf2f(hf[i]) + (1.0f - bta) * bf2f(hb[i]);
  }
};
struct EpiFfn1 {
  const float* b1; u16* a;
  __device__ void operator()(int r, int c, float val) const {
    const float u = val + b1[c];
    const float g = 0.5f * u * (1.0f + erff(u * 0.70710678118f));
    a[(size_t)r * 2048 + c] = f2bf(g);
  }
};
struct EpiFfn2 {
  const float* b2; const float* x2; float* o;
  __device__ void operator()(int r, int c, float val) const {
    const size_t i = (size_t)r * Dq + c;
    o[i] = val + b2[c] + x2[i];
  }
};

// ---------------- bf16 MFMA GEMM: C = A(MxK) * BT(NxK)^T, 256x128 tile ----
// 8 waves (4M x 2N), per-wave 64x64. Ring-3 LDS, prefetch distance 2,
// counted vmcnt(6) (T4), and — new this round — FINE PHASE INTERLEAVE (T3):
// each K-step is 2 barrier-paired phases (one per kk):
//   { 8 ds_read + 3 stage-loads -> barrier -> lgkmcnt(0) -> sched_barrier
//     -> setprio(1) -> 16 MFMA -> setprio(0) -> lgkmcnt(0)
//     -> [end-of-step: vmcnt(6|0)] -> barrier }
// Phase p's MFMAs execute in the matrix pipe while all waves issue phase
// p+1's ds_reads/stages after the closing barrier -> LDS and MFMA pipes
// alternate instead of serializing (the r7 coarse-phase failure).
// Safety: lgkmcnt(0) before EVERY closing barrier means no wave ever has an
// LDS read outstanding across a barrier -> ring overwrite race impossible;
// vmcnt waits sit before a barrier (round-5-verified cross-wave discipline).
// Tail: vmcnt(0) for the last two steps (a counted wait there would be
// trivially satisfied without the needed loads having landed).
template<typename Epi>
__global__ __launch_bounds__(512)
void gemm_bt(const u16* __restrict__ A, const u16* __restrict__ A2, int ksplit,
             const u16* __restrict__ BT, int K, int nx, Epi epi) {
  __shared__ u16 As[3][16384];  // 3 x [256][64] bf16, XOR-swizzled rows
  __shared__ u16 Bs[3][8192];   // 3 x [128][64] bf16
  const int tid  = threadIdx.x;
  const int lane = tid & 63;
  const int w    = tid >> 6;    // 0..7
  const int wr   = w >> 1;      // 0..3 (64-row band)
  const int wc   = w & 1;       // 0..1 (64-col band)

  // XCD-aware bijective remap, col-panel fastest within an XCD chunk.
  const int lin = blockIdx.x;
  const int q8  = gridDim.x >> 3;
  const int t   = (lin & 7) * q8 + (lin >> 3);
  const int by  = t / nx;
  const int bx  = t - by * nx;
  const int rowBase = by << 8;   // 256-row tiles
  const int colBase = bx << 7;   // 128-col tiles

  // staging: 64 rows x 128B per issue; linear LDS dest, pre-swizzled source.
  const int srow  = tid >> 3;                              // 0..63
  const int scolE = (((tid & 7) ^ (srow & 7)) << 4) >> 1;  // element col in source row
  const int KA    = (ksplit < K) ? ksplit : K;             // row stride of A buffers

  auto stageA = [&](int buf, int kt, int qq) {
    const int kbase = kt << 6;
    const u16* Abase = (kbase < ksplit) ? A : A2;
    const int  kA    = (kbase < ksplit) ? kbase : (kbase - ksplit);
    const u16* ga = Abase + (size_t)(rowBase + (qq << 6) + srow) * KA + kA + scolE;
    __builtin_amdgcn_global_load_lds(
        (const __attribute__((address_space(1))) void*)ga,
        (__attribute__((address_space(3))) void*)((char*)&As[buf][0] + (qq << 13) + (tid << 4)),
        16, 0, 0);
  };
  auto stageB = [&](int buf, int kt, int qq) {
    const int kbase = kt << 6;
    const u16* gb = BT + (size_t)(colBase + (qq << 6) + srow) * K + kbase + scolE;
    __builtin_amdgcn_global_load_lds(
        (const __attribute__((address_space(1))) void*)gb,
        (__attribute__((address_space(3))) void*)((char*)&Bs[buf][0] + (qq << 13) + (tid << 4)),
        16, 0, 0);
  };

  f32x4 acc[4][4];
#pragma unroll
  for (int m = 0; m < 4; ++m)
#pragma unroll
    for (int n = 0; n < 4; ++n) acc[m][n] = (f32x4){0.f, 0.f, 0.f, 0.f};

  const int nkt = K >> 6;       // 16 or 32
  // prologue: stage K-tiles 0 and 1 (6 loads each)
#pragma unroll
  for (int qq = 0; qq < 4; ++qq) { stageA(0, 0, qq); }
  stageB(0, 0, 0); stageB(0, 0, 1);
#pragma unroll
  for (int qq = 0; qq < 4; ++qq) { stageA(1, 1, qq); }
  stageB(1, 1, 0); stageB(1, 1, 1);
  asm volatile("s_waitcnt vmcnt(6)" ::: "memory");   // K-tile 0 resident
  __builtin_amdgcn_s_barrier();

  int cbuf = 0, sbuf = 2;
  for (int j = 0; j < nkt; ++j) {
    const bool st = (j + 2) < nkt;
    const int kt2 = j + 2;
    const char* Ab = (const char*)&As[cbuf][0];
    const char* Bb = (const char*)&Bs[cbuf][0];

#pragma unroll
    for (int kk = 0; kk < 2; ++kk) {
      // ---- phase reads (8 ds_read_b128) ----
      bf16x8 af[4], bfr[4];
      const int cb = (kk << 6) + ((lane >> 4) << 4);
#pragma unroll
      for (int m = 0; m < 4; ++m) {
        const int r = (wr << 6) + (m << 4) + (lane & 15);
        af[m] = *(const bf16x8*)(Ab + (r << 7) + (cb ^ ((r & 7) << 4)));
      }
#pragma unroll
      for (int n = 0; n < 4; ++n) {
        const int r = (wc << 6) + (n << 4) + (lane & 15);
        bfr[n] = *(const bf16x8*)(Bb + (r << 7) + (cb ^ ((r & 7) << 4)));
      }
      // ---- phase stage (3 global_load_lds) ----
      if (st) {
        if (kk == 0) { stageA(sbuf, kt2, 0); stageA(sbuf, kt2, 1); stageA(sbuf, kt2, 2); }
        else         { stageA(sbuf, kt2, 3); stageB(sbuf, kt2, 0); stageB(sbuf, kt2, 1); }
      }
      // ---- opening barrier: all waves' reads issued; own reads drained ----
      __builtin_amdgcn_s_barrier();
      asm volatile("s_waitcnt lgkmcnt(0)" ::: "memory");
      __builtin_amdgcn_sched_barrier(0);
      __builtin_amdgcn_s_setprio(1);
#pragma unroll
      for (int m = 0; m < 4; ++m)
#pragma unroll
        for (int n = 0; n < 4; ++n)
          acc[m][n] = __builtin_amdgcn_mfma_f32_16x16x32_bf16(af[m], bfr[n], acc[m][n], 0, 0, 0);
      __builtin_amdgcn_s_setprio(0);
      // no LDS read may be outstanding across the closing barrier
      asm volatile("s_waitcnt lgkmcnt(0)" ::: "memory");
      if (kk == 1) {
        if (j < nkt - 2) asm volatile("s_waitcnt vmcnt(6)" ::: "memory");
        else             asm volatile("s_waitcnt vmcnt(0)" ::: "memory");
      }
      __builtin_amdgcn_s_barrier();   // closing barrier
    }
    cbuf = (cbuf == 2) ? 0 : cbuf + 1;
    sbuf = (sbuf == 2) ? 0 : sbuf + 1;
  }

  // epilogue: C/D layout col = lane&15, row = (lane>>4)*4 + reg
#pragma unroll
  for (int m = 0; m < 4; ++m) {
    const int grow0 = rowBase + (wr << 6) + (m << 4) + ((lane >> 4) << 2);
#pragma unroll
    for (int n = 0; n < 4; ++n) {
      const int gcol = colBase + (wc << 6) + (n << 4) + (lane & 15);
#pragma unroll
      for (int r2 = 0; r2 < 4; ++r2)
        epi(grow0 + r2, gcol, acc[m][n][r2]);
    }
  }
}

// ---------------- launcher ----------------
extern "C" void kernel_launch(void* const* d_in, const int* in_sizes, int n_in,
                              void* d_out, int out_size, void* d_ws, size_t ws_size,
                              hipStream_t stream) {
  (void)in_sizes; (void)n_in; (void)out_size; (void)ws_size;
  const float* x      = (const float*)d_in[0];
  const float* mask   = (const float*)d_in[1];
  const float* ln1w   = (const float*)d_in[2];
  const float* ln1b   = (const float*)d_in[3];
  const float* ln2w   = (const float*)d_in[4];
  const float* ln2b   = (const float*)d_in[5];
  const float* Wg_f   = (const float*)d_in[6];
  const float* bg_f   = (const float*)d_in[7];
  const float* Wg_b   = (const float*)d_in[8];
  const float* bg_b   = (const float*)d_in[9];
  const float* W_fuse = (const float*)d_in[10];
  const float* b_fuse = (const float*)d_in[11];
  const float* W_ffn1 = (const float*)d_in[12];
  const float* b_ffn1 = (const float*)d_in[13];
  const float* W_ffn2 = (const float*)d_in[14];
  const float* b_ffn2 = (const float*)d_in[15];
  float* out = (float*)d_out;

  // ---- workspace layout: ~178 MiB total ----
  char* ws = (char*)d_ws;
  size_t off = 0;
  auto alloc = [&](size_t bytes) { char* p = ws + off; off += (bytes + 255) & ~(size_t)255; return p; };
  float* x2     = (float*)alloc((size_t)Mq * Dq * 4);      // 64 MiB, live steps 7-10
  u16*   slotA  = (u16*)  alloc((size_t)Mq * Dq * 2);      // 32 MiB: h_bf16 -> y2
  u16*   hf_bf  = (u16*)  alloc((size_t)Mq * Dq * 2);      // 32 MiB: v_fwd -> h_fwd (in place) -> a lo
  u16*   hb_bf  = (u16*)  alloc((size_t)Mq * Dq * 2);      // 32 MiB: v_bwd -> h_bwd (in place) -> a hi
  u16*   WgT    = (u16*)  alloc((size_t)2048 * 1024 * 2);  // 4 MiB [2048][1024] (fwd rows | bwd rows)
  u16*   WfuT   = (u16*)  alloc((size_t)1024 * 2048 * 2);  // 4 MiB [1024][2048]
  u16*   Wf1T   = (u16*)  alloc((size_t)2048 * 1024 * 2);  // 4 MiB [2048][1024]
  u16*   Wf2T   = (u16*)  alloc((size_t)1024 * 2048 * 2);  // 4 MiB [1024][2048]
  float* ce     = (float*)alloc((size_t)Bq * NCHq * Dq * 4); // 1 MiB (shared both dirs)
  float* car    = (float*)alloc((size_t)Bq * NCHq * Dq * 4); // 1 MiB
  u16*   h_bf16 = slotA;
  u16*   y2     = slotA;
  u16*   a_bf16 = hf_bf;   // hf|hb contiguous 64 MiB -> [M][2048] FFN1 activations

  // 1. weight prep (transpose + bf16); gate weights concatenated along N
  transpose_bf16<<<dim3(32, 32), 256, 0, stream>>>(Wg_f, WgT, 1024, 1024);
  transpose_bf16<<<dim3(32, 32), 256, 0, stream>>>(Wg_b, WgT + 1024 * 1024, 1024, 1024);
  transpose_bf16<<<dim3(32, 64), 256, 0, stream>>>(W_fuse, WfuT, 2048, 1024);
  transpose_bf16<<<dim3(64, 32), 256, 0, stream>>>(W_ffn1, Wf1T, 1024, 2048);
  transpose_bf16<<<dim3(32, 64), 256, 0, stream>>>(W_ffn2, Wf2T, 2048, 1024);

  // 2. LN1: x -> h_bf16
  ln_kernel<<<Mq, 256, 0, stream>>>(x, ln1w, ln1b, h_bf16);

  const int sg = Bq * NCHq * (Dq / 256);

  // 3. merged gate GEMM (N=2048 = fwd|bwd) -> v_fwd, v_bwd (bf16)
  EpiGate eg{h_bf16, mask, bg_f, bg_b, hf_bf, hb_bf};
  gemm_bt<EpiGate><<<16 * (Mq / 256), 512, 0, stream>>>(h_bf16, h_bf16, 1024, WgT, 1024, 16, eg);

  // 4. decay scans, in-place bf16 v -> h
  scan_pass1<false><<<sg, 256, 0, stream>>>(hf_bf, ce);
  scan_pass2<<<(Bq * Dq) / 256, 256, 0, stream>>>(ce, car);
  scan_pass3<false><<<sg, 256, 0, stream>>>(hf_bf, car);
  scan_pass1<true ><<<sg, 256, 0, stream>>>(hb_bf, ce);
  scan_pass2<<<(Bq * Dq) / 256, 256, 0, stream>>>(ce, car);
  scan_pass3<true ><<<sg, 256, 0, stream>>>(hb_bf, car);

  // 7. fusion GEMM (K=2048, A split hf|hb), epilogue: beta-blend + residual -> x2
  EpiFuse ef{b_fuse, x, hf_bf, hb_bf, x2};
  gemm_bt<EpiFuse><<<8 * (Mq / 256), 512, 0, stream>>>(hf_bf, hb_bf, 1024, WfuT, 2048, 8, ef);

  // 8. LN2: x2 -> y2 (overwrites h_bf16 slot, no longer needed)
  ln_kernel<<<Mq, 256, 0, stream>>>(x2, ln2w, ln2b, y2);

  // 9. FFN1 (N=2048) + exact GELU -> a_bf16 (overwrites hf|hb, dead after fuse)
  EpiFfn1 e1{b_ffn1, a_bf16};
  gemm_bt<EpiFfn1><<<16 * (Mq / 256), 512, 0, stream>>>(y2, y2, 1024, Wf1T, 1024, 16, e1);

  // 10. FFN2 (K=2048) + bias + residual -> out
  EpiFfn2 e2{b_ffn2, x2, out};
  gemm_bt<EpiFfn2><<<8 * (Mq / 256), 512, 0, stream>>>(a_bf16, a_bf16, 2048, Wf2T, 2048, 8, e2);
}